// Round 11
// baseline (558.632 us; speedup 1.0000x reference)
//
#include <hip/hip_runtime.h>

typedef unsigned short u16;
typedef unsigned int   u32;
typedef unsigned long long u64;
typedef __attribute__((ext_vector_type(8))) short short8;
typedef __attribute__((ext_vector_type(4))) float f32x4;

#define T_TOK 8192
#define DIM   1024
#define NEXP  8
#define NPAIR (T_TOK * 2)   // 16384 token-expert pairs
#define MAXTILES 136        // sum ceil(cnt_e/128) <= 135; 136 % 8 == 0

__device__ __forceinline__ u16 f2bf(float f) {
  u32 u = __builtin_bit_cast(u32, f);
  u32 r = (u + 0x7fffu + ((u >> 16) & 1u)) >> 16;  // RNE
  return (u16)r;
}
__device__ __forceinline__ float bf2f(u16 b) {
  return __builtin_bit_cast(float, ((u32)b) << 16);
}

__device__ __forceinline__ void gl_lds16(const u16* g, u16* l) {
  __builtin_amdgcn_global_load_lds(
      (const __attribute__((address_space(1))) u32*)g,
      (__attribute__((address_space(3))) u32*)l,
      16, 0, 0);
}

// ---------------- fused prep: cast x/W1/W2 to bf16 + pair sort ---------------
// Block 0: single-block ballot sort (hides under the BW-bound cast stream).
// Blocks 1..3072: fp32->bf16 cast. R3/R4/R6 lessons: no gates, no dynamic
// claiming, no atomics — kernel boundaries are the cheap sync on this chip.
__global__ void prep_k(const float* __restrict__ x, const float* __restrict__ W1,
                       const float* __restrict__ W2,
                       u16* __restrict__ xb, u16* __restrict__ w1b, u16* __restrict__ w2b,
                       const int* __restrict__ idx,
                       int* __restrict__ counts, int* __restrict__ offsets,
                       int* __restrict__ bucket, int* __restrict__ pos,
                       int* __restrict__ tlist, int* __restrict__ ntiles) {
  __shared__ int lc[16][NEXP];
  __shared__ int lo[16][NEXP];

  if (blockIdx.x != 0) {
    // ---- cast path: 3072 blocks x 1024 threads x 8 elems = 3 x 8388608 ----
    const int g = ((int)(blockIdx.x - 1) * 1024 + (int)threadIdx.x) * 8;
    const int region = g >> 23;                      // 8388608 elems per region
    const int i = g & 0x7fffff;
    const float* s = (region == 0) ? x : (region == 1) ? W1 : W2;
    u16* d = (region == 0) ? xb : (region == 1) ? w1b : w2b;
    f32x4 a = *(const f32x4*)(s + i);
    f32x4 b = *(const f32x4*)(s + i + 4);
    short8 o;
    o[0] = (short)f2bf(a[0]); o[1] = (short)f2bf(a[1]);
    o[2] = (short)f2bf(a[2]); o[3] = (short)f2bf(a[3]);
    o[4] = (short)f2bf(b[0]); o[5] = (short)f2bf(b[1]);
    o[6] = (short)f2bf(b[2]); o[7] = (short)f2bf(b[3]);
    *(short8*)(d + i) = o;
    return;
  }

  // ---- sort path: bucket pairs by expert, ballot-based, no atomics ----
  // Emits tlist ROUND-ROBIN over experts so tile-slot p has expert p%8,
  // enabling the expert->XCD L2-locality swizzle in the GEMM.
  const int tid  = threadIdx.x;
  const int w    = tid >> 6;
  const int lane = tid & 63;
  const u64 ltmask = (lane == 63) ? 0x7fffffffffffffffull : ((1ull << lane) - 1);

  int e_i[16];
#pragma unroll
  for (int i = 0; i < 16; ++i) e_i[i] = idx[(w * 16 + i) * 64 + lane];

  int cnt[NEXP] = {};
#pragma unroll
  for (int i = 0; i < 16; ++i) {
#pragma unroll
    for (int ex = 0; ex < NEXP; ++ex) {
      u64 m = __ballot(e_i[i] == ex);
      cnt[ex] += (int)__popcll(m);
    }
  }
  if (lane == 0) {
#pragma unroll
    for (int ex = 0; ex < NEXP; ++ex) lc[w][ex] = cnt[ex];
  }
  __syncthreads();

  if (tid == 0) {
    int s = 0;
    int c8[NEXP];
    for (int ex = 0; ex < NEXP; ++ex) {
      offsets[ex] = s;
      int c = 0;
      for (int ww = 0; ww < 16; ++ww) { lo[ww][ex] = s; s += lc[ww][ex]; c += lc[ww][ex]; }
      counts[ex] = c;
      c8[ex] = c;
    }
    int t = 0;  // round-robin emission: slot p -> expert p%8 while rounds full
    for (int r = 0; r < 128; ++r)
      for (int ex = 0; ex < NEXP; ++ex)
        if (r * 128 < c8[ex]) tlist[t++] = (r << 3) | ex;
    *ntiles = t;
  }
  __syncthreads();

  int cur[NEXP];
#pragma unroll
  for (int ex = 0; ex < NEXP; ++ex) cur[ex] = lo[w][ex];
#pragma unroll
  for (int i = 0; i < 16; ++i) {
    const int item = (w * 16 + i) * 64 + lane;
    const int e = e_i[i];
    int p = 0;
#pragma unroll
    for (int ex = 0; ex < NEXP; ++ex) {
      u64 m = __ballot(e == ex);
      int rank = (int)__popcll(m & ltmask);
      if (e == ex) p = cur[ex] + rank;
      cur[ex] += (int)__popcll(m);
    }
    bucket[p] = item;
    pos[item] = p;
  }
}

// ---------------- grouped GEMM: O[p] = relu(Arow[p] @ W[e]^T), bf16 ----------
// 128x128 tile, BK=32 K-steps, double-buffered LDS at 4x8KB = 32KB total ->
// 4 blocks/CU kept (R7 lesson: dbuf at 2 blocks/CU loses TLP > gains ILP).
// Pipeline (statically unrolled 2-step body, NAMED buffers — no pointer swap,
// no runtime-indexed buffer select; R8's swap variant never produced data):
//   stage(t+1 -> buf1); compute(buf0); barrier;
//   stage(t+2 -> buf0); compute(buf1); barrier;
// The barrier's implicit vmcnt(0) drain is hidden under the compute phase
// (R2's issue->drain->compute serial order exposed it). 31 barriers = R2's 32.
//
// LDS geometry: two tile-rows folded per 128B LDS row ([64 rows][128B]) so the
// 8-chunk XOR swizzle applies. Staging applies the inverse permutation on the
// GLOBAL source address (both-sides-or-neither, m104/m231): LDS chunk c=(R,pl)
// sources global (r = 2R + ((pl^(R&7))>>2), q = (pl^(R&7))&3). Read of tile
// row r, k-quad `quad`: LDS pos (((r&1)<<2)+quad) ^ ((r>>1)&7). Bank math per
// 16-lane ds_read_b128 group: each swizzle pos hit exactly 2x -> every bank
// covered 2x -> 2-way = free (m136).
//
// Grid (136, 8): blockIdx.x = tile slot, expert = slot%8 (round-robin tlist)
// -> XCD pinning since gridDim.x%8==0 (worth 6.6x on FETCH, R3 lesson).
// __launch_bounds__(256,4): R1 lesson — 5 forces spill.
template <int GATHER>
__global__ __launch_bounds__(256, 4)
void moe_gemm_k(const u16* __restrict__ A,
                const u16* __restrict__ W,
                u16* __restrict__ O,
                const int* __restrict__ counts,
                const int* __restrict__ offsets,
                const int* __restrict__ bucket,
                const int* __restrict__ tlist,
                const int* __restrict__ ntiles) {
  if ((int)blockIdx.x >= *ntiles) return;
  const int info = tlist[blockIdx.x];
  const int e    = info & 7;
  const int m0   = (info >> 3) << 7;
  const int cnt  = counts[e];
  const int seg  = offsets[e];
  const int n0   = blockIdx.y << 7;

  __shared__ u16 As0[4096];  // 8 KB: [64 LDS-rows][64 u16 = 128B]
  __shared__ u16 As1[4096];  // 8 KB
  __shared__ u16 Bs0[4096];  // 8 KB
  __shared__ u16 Bs1[4096];  // 8 KB

  const int tid  = threadIdx.x;
  const int lane = tid & 63;
  const int wave = tid >> 6;

  // Staging: per K-step each matrix = 512 chunks of 16B; wave issues 2 A + 2 B
  // global_load_lds. Global source address carries the inverse chunk swizzle.
  int aoff[2], boff[2];
#pragma unroll
  for (int j = 0; j < 2; ++j) {
    const int c  = ((wave << 1) + j) * 64 + lane;   // LDS chunk 0..511
    const int R  = c >> 3;                          // LDS row
    const int pp = (c & 7) ^ (R & 7);               // unswizzled position
    const int q  = pp & 3;                          // 16B col-chunk (k-offset)
    const int r  = (R << 1) + (pp >> 2);            // tile row 0..127
    int p = seg + m0 + r;
    p = (p < seg + cnt) ? p : (seg + cnt - 1);      // clamp tail rows
    int rowbase;
    if (GATHER) { const int pair = bucket[p]; rowbase = (pair >> 1) * DIM; }
    else        { rowbase = p * DIM; }
    aoff[j] = rowbase + (q << 3);
    boff[j] = e * DIM * DIM + (n0 + r) * DIM + (q << 3);
  }

  f32x4 acc[4][4] = {};

  const int wm   = (wave >> 1) << 6;
  const int wn   = (wave & 1) << 6;
  const int lr   = lane & 15;
  const int quad = lane >> 4;

  // Loop-invariant ds_read element offsets (no kk loop at BK=32).
  int ard[4], brd[4];
#pragma unroll
  for (int mi = 0; mi < 4; ++mi) {
    const int r = wm + (mi << 4) + lr;
    const int R = r >> 1;
    ard[mi] = (R << 6) + (((((r & 1) << 2) + quad) ^ (R & 7)) << 3);
  }
#pragma unroll
  for (int ni = 0; ni < 4; ++ni) {
    const int r = wn + (ni << 4) + lr;
    const int R = r >> 1;
    brd[ni] = (R << 6) + (((((r & 1) << 2) + quad) ^ (R & 7)) << 3);
  }

#define STAGE_K(k0, Adst, Bdst)                                          \
  {                                                                      \
    _Pragma("unroll")                                                    \
    for (int j = 0; j < 2; ++j) {                                        \
      const int instr = (wave << 1) + j;                                 \
      gl_lds16(A + aoff[j] + (k0), &Adst[instr << 9]);                   \
      gl_lds16(W + boff[j] + (k0), &Bdst[instr << 9]);                   \
    }                                                                    \
  }

#define COMPUTE_K(Asrc, Bsrc)                                            \
  {                                                                      \
    short8 af[4], bf[4];                                                 \
    _Pragma("unroll")                                                    \
    for (int mi = 0; mi < 4; ++mi) af[mi] = *(const short8*)&Asrc[ard[mi]]; \
    _Pragma("unroll")                                                    \
    for (int ni = 0; ni < 4; ++ni) bf[ni] = *(const short8*)&Bsrc[brd[ni]]; \
    _Pragma("unroll")                                                    \
    for (int mi = 0; mi < 4; ++mi)                                       \
      _Pragma("unroll")                                                  \
      for (int ni = 0; ni < 4; ++ni)                                     \
        acc[mi][ni] = __builtin_amdgcn_mfma_f32_16x16x32_bf16(           \
            af[mi], bf[ni], acc[mi][ni], 0, 0, 0);                       \
  }

  // Prologue: stage K-step 0 into buffer 0; barrier drains it.
  STAGE_K(0, As0, Bs0);
  __syncthreads();

  // 16 iterations x 2 K-steps = 32 K-steps of 32. Static buffer names.
  for (int t = 0; t < DIM / 32; t += 2) {
    STAGE_K((t + 1) << 5, As1, Bs1);   // fly under compute(buf0)
    COMPUTE_K(As0, Bs0);
    __syncthreads();                   // vmcnt(0): buf1 ready; buf0 free
    if (t + 2 < DIM / 32) {
      STAGE_K((t + 2) << 5, As0, Bs0); // fly under compute(buf1)
      COMPUTE_K(As1, Bs1);
      __syncthreads();                 // vmcnt(0): buf0 ready; buf1 free
    } else {
      COMPUTE_K(As1, Bs1);             // last K-step: nothing to prefetch
    }
  }
#undef STAGE_K
#undef COMPUTE_K

  // Epilogue: relu -> bf16. C/D layout: col = lane&15, row = quad*4 + reg.
  const int pend = seg + cnt;
#pragma unroll
  for (int mi = 0; mi < 4; ++mi) {
#pragma unroll
    for (int ni = 0; ni < 4; ++ni) {
      const int col = n0 + wn + (ni << 4) + lr;
#pragma unroll
      for (int r4 = 0; r4 < 4; ++r4) {
        const int p = seg + m0 + wm + (mi << 4) + (quad << 2) + r4;
        if (p < pend) {
          float v = acc[mi][ni][r4];
          v = v > 0.f ? v : 0.f;
          O[(size_t)p * DIM + col] = f2bf(v);
        }
      }
    }
  }
}

// ---------------- combine: out[t] = w0*y[pos[2t]] + w1*y[pos[2t+1]] ----------
__global__ void combine_k(const u16* __restrict__ y, const int* __restrict__ pos,
                          const float* __restrict__ wts, float* __restrict__ out) {
  const int t    = blockIdx.x * 2 + (threadIdx.x >> 7);
  const int lane = threadIdx.x & 127;
  const int col  = lane * 8;
  const int p0 = pos[2 * t], p1 = pos[2 * t + 1];
  const float w0 = wts[2 * t], w1 = wts[2 * t + 1];
  const short8 a = *(const short8*)(y + (size_t)p0 * DIM + col);
  const short8 b = *(const short8*)(y + (size_t)p1 * DIM + col);
  f32x4 o0, o1;
#pragma unroll
  for (int j = 0; j < 8; ++j) {
    float v = w0 * bf2f((u16)a[j]) + w1 * bf2f((u16)b[j]);
    if (j < 4) o0[j] = v; else o1[j - 4] = v;
  }
  float* op = out + (size_t)t * DIM + col;
  *(f32x4*)op = o0;
  *(f32x4*)(op + 4) = o1;
}

extern "C" void kernel_launch(void* const* d_in, const int* in_sizes, int n_in,
                              void* d_out, int out_size, void* d_ws, size_t ws_size,
                              hipStream_t stream) {
  const float* x   = (const float*)d_in[0];
  const int*   idx = (const int*)d_in[1];
  const float* wts = (const float*)d_in[2];
  const float* W1  = (const float*)d_in[3];
  const float* W2  = (const float*)d_in[4];
  float* out = (float*)d_out;

  char* ws = (char*)d_ws;
  int* counts  = (int*)ws;                       // 8
  int* offsets = (int*)(ws + 32);                // 8
  int* ntiles  = (int*)(ws + 64);                // 1
  int* tlist   = (int*)(ws + 128);               // <=136
  int* bucket  = (int*)(ws + 1024);              // 16384
  int* pos     = (int*)(ws + 1024 + 4 * NPAIR);  // 16384
  const size_t base = 132096;                    // 16B-aligned
  const size_t MB16 = 16ull * 1024 * 1024;
  u16* xb  = (u16*)(ws + base);                  // 16 MB
  u16* w1b = (u16*)(ws + base + MB16);           // 16 MB
  u16* w2b = (u16*)(ws + base + 2 * MB16);       // 16 MB
  u16* h   = (u16*)(ws + base + 3 * MB16);       // 32 MB
  u16* yb  = xb;                                 // 32 MB, aliases xb+w1b (dead)

  // block 0 = sort (starts first, hides under the cast stream)
  prep_k<<<3 * 1024 + 1, 1024, 0, stream>>>(x, W1, W2, xb, w1b, w2b,
                                            idx, counts, offsets, bucket, pos,
                                            tlist, ntiles);

  dim3 gg(MAXTILES, DIM / 128);  // (136, 8): x = tile slot -> XCD = expert
  moe_gemm_k<1><<<gg, 256, 0, stream>>>(xb, w1b, h, counts, offsets, bucket, tlist, ntiles);
  moe_gemm_k<0><<<gg, 256, 0, stream>>>(h, w2b, yb, counts, offsets, bucket, tlist, ntiles);

  combine_k<<<T_TOK / 2, 256, 0, stream>>>(yb, pos, wts, out);
}

// Round 12
// 248.436 us; speedup vs baseline: 2.2486x; 2.2486x over previous
//
#include <hip/hip_runtime.h>

typedef unsigned short u16;
typedef unsigned int   u32;
typedef unsigned long long u64;
typedef __attribute__((ext_vector_type(8))) short short8;
typedef __attribute__((ext_vector_type(4))) float f32x4;

#define T_TOK 8192
#define DIM   1024
#define NEXP  8
#define NPAIR (T_TOK * 2)   // 16384 token-expert pairs
#define MAXTILES 136        // sum ceil(cnt_e/128) <= 128 + 7; 136 % 8 == 0

__device__ __forceinline__ u16 f2bf(float f) {
  u32 u = __builtin_bit_cast(u32, f);
  u32 r = (u + 0x7fffu + ((u >> 16) & 1u)) >> 16;  // RNE
  return (u16)r;
}
__device__ __forceinline__ float bf2f(u16 b) {
  return __builtin_bit_cast(float, ((u32)b) << 16);
}

__device__ __forceinline__ void gl_lds16(const u16* g, u16* l) {
  __builtin_amdgcn_global_load_lds(
      (const __attribute__((address_space(1))) u32*)g,
      (__attribute__((address_space(3))) u32*)l,
      16, 0, 0);
}

// ---------------- fused prep: cast x/W1/W2 to bf16 + pair sort ---------------
// Block 0 runs the single-block ballot sort; blocks 1..3072 stream the
// fp32->bf16 cast (1024 thr x 8 elems). The ~10us serial sort hides under the
// BW-bound cast (measured: saved ~33us of non-GEMM time vs separate launch).
// Session lessons (R3/R4/R6, thrice-measured): no in-kernel gates, no dynamic
// claiming, no atomic combine — kernel boundaries are the cheap sync (~25us);
// device-scope handoff mechanisms cost 40-1000us in stalls/traffic.
__global__ void prep_k(const float* __restrict__ x, const float* __restrict__ W1,
                       const float* __restrict__ W2,
                       u16* __restrict__ xb, u16* __restrict__ w1b, u16* __restrict__ w2b,
                       const int* __restrict__ idx,
                       int* __restrict__ counts, int* __restrict__ offsets,
                       int* __restrict__ bucket, int* __restrict__ pos,
                       int* __restrict__ tlist, int* __restrict__ ntiles) {
  __shared__ int lc[16][NEXP];
  __shared__ int lo[16][NEXP];

  if (blockIdx.x != 0) {
    // ---- cast path: 3072 blocks x 1024 threads x 8 elems = 3 x 8388608 ----
    const int g = ((int)(blockIdx.x - 1) * 1024 + (int)threadIdx.x) * 8;
    const int region = g >> 23;                      // 8388608 elems per region
    const int i = g & 0x7fffff;
    const float* s = (region == 0) ? x : (region == 1) ? W1 : W2;
    u16* d = (region == 0) ? xb : (region == 1) ? w1b : w2b;
    f32x4 a = *(const f32x4*)(s + i);
    f32x4 b = *(const f32x4*)(s + i + 4);
    short8 o;
    o[0] = (short)f2bf(a[0]); o[1] = (short)f2bf(a[1]);
    o[2] = (short)f2bf(a[2]); o[3] = (short)f2bf(a[3]);
    o[4] = (short)f2bf(b[0]); o[5] = (short)f2bf(b[1]);
    o[6] = (short)f2bf(b[2]); o[7] = (short)f2bf(b[3]);
    *(short8*)(d + i) = o;
    return;
  }

  // ---- sort path: bucket pairs by expert, ballot-based, no atomics ----
  // Emits tlist ROUND-ROBIN over experts so tile-slot p has expert p%8,
  // enabling the expert->XCD L2-locality swizzle in the GEMM.
  const int tid  = threadIdx.x;
  const int w    = tid >> 6;
  const int lane = tid & 63;
  const u64 ltmask = (lane == 63) ? 0x7fffffffffffffffull : ((1ull << lane) - 1);

  int e_i[16];
#pragma unroll
  for (int i = 0; i < 16; ++i) e_i[i] = idx[(w * 16 + i) * 64 + lane];

  int cnt[NEXP] = {};
#pragma unroll
  for (int i = 0; i < 16; ++i) {
#pragma unroll
    for (int ex = 0; ex < NEXP; ++ex) {
      u64 m = __ballot(e_i[i] == ex);
      cnt[ex] += (int)__popcll(m);
    }
  }
  if (lane == 0) {
#pragma unroll
    for (int ex = 0; ex < NEXP; ++ex) lc[w][ex] = cnt[ex];
  }
  __syncthreads();

  if (tid == 0) {
    int s = 0;
    int c8[NEXP];
    for (int ex = 0; ex < NEXP; ++ex) {
      offsets[ex] = s;
      int c = 0;
      for (int ww = 0; ww < 16; ++ww) { lo[ww][ex] = s; s += lc[ww][ex]; c += lc[ww][ex]; }
      counts[ex] = c;
      c8[ex] = c;
    }
    int t = 0;  // round-robin emission: slot p -> expert p%8 while rounds full
    for (int r = 0; r < 128; ++r)
      for (int ex = 0; ex < NEXP; ++ex)
        if (r * 128 < c8[ex]) tlist[t++] = (r << 3) | ex;
    *ntiles = t;
  }
  __syncthreads();

  int cur[NEXP];
#pragma unroll
  for (int ex = 0; ex < NEXP; ++ex) cur[ex] = lo[w][ex];
#pragma unroll
  for (int i = 0; i < 16; ++i) {
    const int item = (w * 16 + i) * 64 + lane;
    const int e = e_i[i];
    int p = 0;
#pragma unroll
    for (int ex = 0; ex < NEXP; ++ex) {
      u64 m = __ballot(e == ex);
      int rank = (int)__popcll(m & ltmask);
      if (e == ex) p = cur[ex] + rank;
      cur[ex] += (int)__popcll(m);
    }
    bucket[p] = item;
    pos[item] = p;
  }
}

// ---------------- grouped GEMM: O[p] = relu(Arow[p] @ W[e]^T), bf16 ----------
// 128x128x64 K-tiles, single-buffered 32KB LDS, XOR-swizzled layout
// (bank-conflict-free), global_load_lds width-16 staging, 16x16x32 bf16 MFMA,
// 4 waves (2x2), 4x4 frags. Grid (MAXTILES, 8): blockIdx.x = tile slot,
// expert = slot%8 (round-robin tlist) -> XCD pinning since gridDim.x%8==0
// (R3 lesson: this pinning is worth 6.6x on FETCH).
//
// __launch_bounds__(256, 4): 4 blocks/CU = 1024 slots; 1088 blocks pack at
// 94%. Register arithmetic: 60 VGPR + 64 AGPR = 124 <= 128/wave budget at 4
// waves/SIMD -> no spill, 4 regs slack.
//
// This plain 2-barrier loop is the measured optimum of this structure
// (50.3us, verified twice). Session A/Bs that bracketed it:
//   R1:  5 blocks/CU            -> spill (102-reg budget), 2x slower.
//   R7:  dbuf BK=64, 2 blocks/CU -> 63us (TLP loss > ILP gain).
//   R11: dbuf BK=32, 4 blocks/CU -> spill (pipeline live ranges need > 4
//        slack regs), 4x slower. Software pipelining is register-infeasible
//        at this occupancy; matches guide m99/m100/m131-140 (implicit
//        multi-block wave overlap already captures the gain).
//
// Swizzle: tile row r holds its 8 16B-chunks permuted by XOR(r&7). Staging
// lane loads global chunk (c&7)^(r&7) into linear LDS chunk c; fragment read
// of global chunk q reads LDS chunk q^(r&7). Each 16-lane ds_read_b128 group
// then covers all 32 banks exactly 2x (2-way = free, m136).
template <int GATHER>
__global__ __launch_bounds__(256, 4)
void moe_gemm_k(const u16* __restrict__ A,
                const u16* __restrict__ W,
                u16* __restrict__ O,
                const int* __restrict__ counts,
                const int* __restrict__ offsets,
                const int* __restrict__ bucket,
                const int* __restrict__ tlist,
                const int* __restrict__ ntiles) {
  if ((int)blockIdx.x >= *ntiles) return;
  const int info = tlist[blockIdx.x];
  const int e    = info & 7;
  const int m0   = (info >> 3) << 7;
  const int cnt  = counts[e];
  const int seg  = offsets[e];
  const int n0   = blockIdx.y << 7;

  __shared__ u16 As[128 * 64];  // 16 KB, row-major [r][64] with chunk swizzle
  __shared__ u16 Bs[128 * 64];  // 16 KB

  const int tid  = threadIdx.x;
  const int lane = tid & 63;
  const int wave = tid >> 6;

  // Staging: tile = 1024 chunks of 16B per matrix; wave issues 4 A + 4 B
  // global_load_lds per K-iter. Global chunk is XOR-swizzled by row.
  int aoff[4], boff[4];
#pragma unroll
  for (int j = 0; j < 4; ++j) {
    const int c   = ((wave << 2) + j) * 64 + lane;  // chunk 0..1023
    const int r   = c >> 3;                         // tile row
    const int c16 = (c & 7) ^ (r & 7);              // swizzled 16B chunk
    int p = seg + m0 + r;
    p = (p < seg + cnt) ? p : (seg + cnt - 1);      // clamp tail rows
    int rowbase;
    if (GATHER) { const int pair = bucket[p]; rowbase = (pair >> 1) * DIM; }
    else        { rowbase = p * DIM; }
    aoff[j] = rowbase + (c16 << 3);
    boff[j] = e * DIM * DIM + (n0 + r) * DIM + (c16 << 3);
  }

  f32x4 acc[4][4] = {};

  const int wm   = (wave >> 1) << 6;
  const int wn   = (wave & 1) << 6;
  const int lr   = lane & 15;
  const int quad = lane >> 4;

  for (int k0 = 0; k0 < DIM; k0 += 64) {
    __syncthreads();  // protect LDS reuse
#pragma unroll
    for (int j = 0; j < 4; ++j) {
      const int instr = (wave << 2) + j;
      gl_lds16(A + aoff[j] + k0, &As[instr << 9]);
      gl_lds16(W + boff[j] + k0, &Bs[instr << 9]);
    }
    __syncthreads();  // drains vmcnt for global_load_lds

#pragma unroll
    for (int kk = 0; kk < 64; kk += 32) {
      const int qb = (kk >> 3) + quad;  // wanted global chunk
      short8 af[4], bf[4];
#pragma unroll
      for (int mi = 0; mi < 4; ++mi) {
        const int r = wm + (mi << 4) + lr;
        af[mi] = *(const short8*)&As[r * 64 + ((qb ^ (r & 7)) << 3)];
      }
#pragma unroll
      for (int ni = 0; ni < 4; ++ni) {
        const int r = wn + (ni << 4) + lr;
        bf[ni] = *(const short8*)&Bs[r * 64 + ((qb ^ (r & 7)) << 3)];
      }
#pragma unroll
      for (int mi = 0; mi < 4; ++mi)
#pragma unroll
        for (int ni = 0; ni < 4; ++ni)
          acc[mi][ni] = __builtin_amdgcn_mfma_f32_16x16x32_bf16(af[mi], bf[ni], acc[mi][ni], 0, 0, 0);
    }
  }

  // Epilogue: relu -> bf16. C/D layout: col = lane&15, row = quad*4 + reg.
  const int pend = seg + cnt;
#pragma unroll
  for (int mi = 0; mi < 4; ++mi) {
#pragma unroll
    for (int ni = 0; ni < 4; ++ni) {
      const int col = n0 + wn + (ni << 4) + lr;
#pragma unroll
      for (int r4 = 0; r4 < 4; ++r4) {
        const int p = seg + m0 + wm + (mi << 4) + (quad << 2) + r4;
        if (p < pend) {
          float v = acc[mi][ni][r4];
          v = v > 0.f ? v : 0.f;
          O[(size_t)p * DIM + col] = f2bf(v);
        }
      }
    }
  }
}

// ---------------- combine: out[t] = w0*y[pos[2t]] + w1*y[pos[2t+1]] ----------
__global__ void combine_k(const u16* __restrict__ y, const int* __restrict__ pos,
                          const float* __restrict__ wts, float* __restrict__ out) {
  const int t    = blockIdx.x * 2 + (threadIdx.x >> 7);
  const int lane = threadIdx.x & 127;
  const int col  = lane * 8;
  const int p0 = pos[2 * t], p1 = pos[2 * t + 1];
  const float w0 = wts[2 * t], w1 = wts[2 * t + 1];
  const short8 a = *(const short8*)(y + (size_t)p0 * DIM + col);
  const short8 b = *(const short8*)(y + (size_t)p1 * DIM + col);
  f32x4 o0, o1;
#pragma unroll
  for (int j = 0; j < 8; ++j) {
    float v = w0 * bf2f((u16)a[j]) + w1 * bf2f((u16)b[j]);
    if (j < 4) o0[j] = v; else o1[j - 4] = v;
  }
  float* op = out + (size_t)t * DIM + col;
  *(f32x4*)op = o0;
  *(f32x4*)(op + 4) = o1;
}

extern "C" void kernel_launch(void* const* d_in, const int* in_sizes, int n_in,
                              void* d_out, int out_size, void* d_ws, size_t ws_size,
                              hipStream_t stream) {
  const float* x   = (const float*)d_in[0];
  const int*   idx = (const int*)d_in[1];
  const float* wts = (const float*)d_in[2];
  const float* W1  = (const float*)d_in[3];
  const float* W2  = (const float*)d_in[4];
  float* out = (float*)d_out;

  char* ws = (char*)d_ws;
  int* counts  = (int*)ws;                       // 8
  int* offsets = (int*)(ws + 32);                // 8
  int* ntiles  = (int*)(ws + 64);                // 1
  int* tlist   = (int*)(ws + 128);               // <=136
  int* bucket  = (int*)(ws + 1024);              // 16384
  int* pos     = (int*)(ws + 1024 + 4 * NPAIR);  // 16384
  const size_t base = 132096;                    // 16B-aligned
  const size_t MB16 = 16ull * 1024 * 1024;
  u16* xb  = (u16*)(ws + base);                  // 16 MB
  u16* w1b = (u16*)(ws + base + MB16);           // 16 MB
  u16* w2b = (u16*)(ws + base + 2 * MB16);       // 16 MB
  u16* h   = (u16*)(ws + base + 3 * MB16);       // 32 MB
  u16* yb  = xb;                                 // 32 MB, aliases xb+w1b (dead)

  // block 0 = sort (starts first, hides under the cast stream)
  prep_k<<<3 * 1024 + 1, 1024, 0, stream>>>(x, W1, W2, xb, w1b, w2b,
                                            idx, counts, offsets, bucket, pos,
                                            tlist, ntiles);

  dim3 gg(MAXTILES, DIM / 128);  // (136, 8): x = tile slot -> XCD = expert
  moe_gemm_k<1><<<gg, 256, 0, stream>>>(xb, w1b, h, counts, offsets, bucket, tlist, ntiles);
  moe_gemm_k<0><<<gg, 256, 0, stream>>>(h, w2b, yb, counts, offsets, bucket, tlist, ntiles);

  combine_k<<<T_TOK / 2, 256, 0, stream>>>(yb, pos, wts, out);
}

// Round 13
// 244.693 us; speedup vs baseline: 2.2830x; 1.0153x over previous
//
#include <hip/hip_runtime.h>

typedef unsigned short u16;
typedef unsigned int   u32;
typedef unsigned long long u64;
typedef __attribute__((ext_vector_type(8))) short short8;
typedef __attribute__((ext_vector_type(4))) float f32x4;

#define T_TOK 8192
#define DIM   1024
#define NEXP  8
#define NPAIR (T_TOK * 2)   // 16384 token-expert pairs
#define MAXTILES 136        // sum ceil(cnt_e/128) <= 128 + 7; 136 % 8 == 0
#define GEMM_BLKS 1088      // 136 * 8, 1D grid with tail-last unit mapping

__device__ __forceinline__ u16 f2bf(float f) {
  u32 u = __builtin_bit_cast(u32, f);
  u32 r = (u + 0x7fffu + ((u >> 16) & 1u)) >> 16;  // RNE
  return (u16)r;
}
__device__ __forceinline__ float bf2f(u16 b) {
  return __builtin_bit_cast(float, ((u32)b) << 16);
}

__device__ __forceinline__ void gl_lds16(const u16* g, u16* l) {
  __builtin_amdgcn_global_load_lds(
      (const __attribute__((address_space(1))) u32*)g,
      (__attribute__((address_space(3))) u32*)l,
      16, 0, 0);
}

// ---------------- fused prep: cast x/W1/W2 to bf16 + pair sort ---------------
// Block 0 runs the single-block ballot sort; blocks 1..3072 stream the
// fp32->bf16 cast (1024 thr x 8 elems). The ~10us serial sort hides under the
// BW-bound cast. Session lessons (R3/R4/R6): no in-kernel gates, no dynamic
// claiming, no atomic combine — kernel boundaries are the cheap sync.
__global__ void prep_k(const float* __restrict__ x, const float* __restrict__ W1,
                       const float* __restrict__ W2,
                       u16* __restrict__ xb, u16* __restrict__ w1b, u16* __restrict__ w2b,
                       const int* __restrict__ idx,
                       int* __restrict__ counts, int* __restrict__ offsets,
                       int* __restrict__ bucket, int* __restrict__ pos,
                       int* __restrict__ tlist, int* __restrict__ ntiles) {
  __shared__ int lc[16][NEXP];
  __shared__ int lo[16][NEXP];

  if (blockIdx.x != 0) {
    // ---- cast path: 3072 blocks x 1024 threads x 8 elems = 3 x 8388608 ----
    const int g = ((int)(blockIdx.x - 1) * 1024 + (int)threadIdx.x) * 8;
    const int region = g >> 23;                      // 8388608 elems per region
    const int i = g & 0x7fffff;
    const float* s = (region == 0) ? x : (region == 1) ? W1 : W2;
    u16* d = (region == 0) ? xb : (region == 1) ? w1b : w2b;
    f32x4 a = *(const f32x4*)(s + i);
    f32x4 b = *(const f32x4*)(s + i + 4);
    short8 o;
    o[0] = (short)f2bf(a[0]); o[1] = (short)f2bf(a[1]);
    o[2] = (short)f2bf(a[2]); o[3] = (short)f2bf(a[3]);
    o[4] = (short)f2bf(b[0]); o[5] = (short)f2bf(b[1]);
    o[6] = (short)f2bf(b[2]); o[7] = (short)f2bf(b[3]);
    *(short8*)(d + i) = o;
    return;
  }

  // ---- sort path: bucket pairs by expert, ballot-based, no atomics ----
  // Emits tlist ROUND-ROBIN over experts so tile-slot p has expert p%8
  // (while rounds are full), enabling the expert->XCD swizzle in the GEMM.
  const int tid  = threadIdx.x;
  const int w    = tid >> 6;
  const int lane = tid & 63;
  const u64 ltmask = (lane == 63) ? 0x7fffffffffffffffull : ((1ull << lane) - 1);

  int e_i[16];
#pragma unroll
  for (int i = 0; i < 16; ++i) e_i[i] = idx[(w * 16 + i) * 64 + lane];

  int cnt[NEXP] = {};
#pragma unroll
  for (int i = 0; i < 16; ++i) {
#pragma unroll
    for (int ex = 0; ex < NEXP; ++ex) {
      u64 m = __ballot(e_i[i] == ex);
      cnt[ex] += (int)__popcll(m);
    }
  }
  if (lane == 0) {
#pragma unroll
    for (int ex = 0; ex < NEXP; ++ex) lc[w][ex] = cnt[ex];
  }
  __syncthreads();

  if (tid == 0) {
    int s = 0;
    int c8[NEXP];
    for (int ex = 0; ex < NEXP; ++ex) {
      offsets[ex] = s;
      int c = 0;
      for (int ww = 0; ww < 16; ++ww) { lo[ww][ex] = s; s += lc[ww][ex]; c += lc[ww][ex]; }
      counts[ex] = c;
      c8[ex] = c;
    }
    int t = 0;  // round-robin emission: slot p -> expert p%8 while rounds full
    for (int r = 0; r < 128; ++r)
      for (int ex = 0; ex < NEXP; ++ex)
        if (r * 128 < c8[ex]) tlist[t++] = (r << 3) | ex;
    *ntiles = t;
  }
  __syncthreads();

  int cur[NEXP];
#pragma unroll
  for (int ex = 0; ex < NEXP; ++ex) cur[ex] = lo[w][ex];
#pragma unroll
  for (int i = 0; i < 16; ++i) {
    const int item = (w * 16 + i) * 64 + lane;
    const int e = e_i[i];
    int p = 0;
#pragma unroll
    for (int ex = 0; ex < NEXP; ++ex) {
      u64 m = __ballot(e == ex);
      int rank = (int)__popcll(m & ltmask);
      if (e == ex) p = cur[ex] + rank;
      cur[ex] += (int)__popcll(m);
    }
    bucket[p] = item;
    pos[item] = p;
  }
}

// ---------------- grouped GEMM: O[p] = relu(Arow[p] @ W[e]^T), bf16 ----------
// Core loop = R2's verified 2-barrier structure (50.3us/tile-round, thrice
// measured): 128x128x64 K-tiles, single-buffered 32KB LDS, XOR chunk swizzle,
// global_load_lds width-16 staging, 16x16x32 bf16 MFMA, 4 waves, 4x4 frags.
// __launch_bounds__(256,4): 60 VGPR + 64 AGPR = 124 <= 128 budget (R1: 5/CU
// spills; R7/R11: software pipelining is register-infeasible here).
//
// NEW vs R2 — tail-quantization fix (makespan was ~2*T_tile: 1072 units over
// 1024 slots, with full-cost tiles landing in the overflow round):
//  1) 1D grid 1088 with unit mapping bid<1024 -> (slot=bid&127, n0=bid>>7),
//     bid>=1024 -> (slot=128+(bid-1024)&7, n0=(bid-1024)>>3). First 1024
//     blocks = slots 0..127 (full RR rounds); last 64 = round-16 remainder
//     tiles (few, small). Bijective; bid%8 == slot%8 in both branches ->
//     expert->XCD pinning preserved (R3: worth 6.6x FETCH).
//  2) Wave-uniform M-skip: rows = min(cnt-m0, 128); skip A-staging chunks and
//     af/MFMA frag-rows entirely above `rows` (scalar branches, no dynamic
//     indexing, acc stays statically indexed). Partial tiles now cost ~rows/128
//     of a full tile instead of full price — tail units finish inside the
//     main round's shadow.
template <int GATHER>
__global__ __launch_bounds__(256, 4)
void moe_gemm_k(const u16* __restrict__ A,
                const u16* __restrict__ W,
                u16* __restrict__ O,
                const int* __restrict__ counts,
                const int* __restrict__ offsets,
                const int* __restrict__ bucket,
                const int* __restrict__ tlist,
                const int* __restrict__ ntiles) {
  const int bid = (int)blockIdx.x;
  int slot, n0q;
  if (bid < 1024) { slot = bid & 127;                n0q = bid >> 7; }
  else            { slot = 128 + ((bid - 1024) & 7); n0q = (bid - 1024) >> 3; }
  if (slot >= *ntiles) return;

  const int info = tlist[slot];
  const int e    = info & 7;
  const int m0   = (info >> 3) << 7;
  const int cnt  = counts[e];
  const int seg  = offsets[e];
  const int n0   = n0q << 7;
  const int rows = min(cnt - m0, 128);   // live rows in this tile

  __shared__ u16 As[128 * 64];  // 16 KB, row-major [r][64] with chunk swizzle
  __shared__ u16 Bs[128 * 64];  // 16 KB

  const int tid  = threadIdx.x;
  const int lane = tid & 63;
  const int wave = tid >> 6;

  // Staging: tile = 1024 chunks of 16B per matrix; wave issues up to 4 A + 4 B
  // global_load_lds per K-iter. Global chunk is XOR-swizzled by row.
  int aoff[4], boff[4];
#pragma unroll
  for (int j = 0; j < 4; ++j) {
    const int c   = ((wave << 2) + j) * 64 + lane;  // chunk 0..1023
    const int r   = c >> 3;                         // tile row
    const int c16 = (c & 7) ^ (r & 7);              // swizzled 16B chunk
    int p = seg + m0 + r;
    p = (p < seg + cnt) ? p : (seg + cnt - 1);      // clamp tail rows
    int rowbase;
    if (GATHER) { const int pair = bucket[p]; rowbase = (pair >> 1) * DIM; }
    else        { rowbase = p * DIM; }
    aoff[j] = rowbase + (c16 << 3);
    boff[j] = e * DIM * DIM + (n0 + r) * DIM + (c16 << 3);
  }

  f32x4 acc[4][4] = {};

  const int wm   = (wave >> 1) << 6;
  const int wn   = (wave & 1) << 6;
  const int lr   = lane & 15;
  const int quad = lane >> 4;

  for (int k0 = 0; k0 < DIM; k0 += 64) {
    __syncthreads();  // protect LDS reuse
#pragma unroll
    for (int j = 0; j < 4; ++j) {
      const int instr = (wave << 2) + j;
      // A-chunk j covers tile rows [instr*8, instr*8+8): skip if fully dead
      // (wave-uniform scalar branch; dead rows are never read by any frag).
      if ((instr << 3) < rows)
        gl_lds16(A + aoff[j] + k0, &As[instr << 9]);
      gl_lds16(W + boff[j] + k0, &Bs[instr << 9]);
    }
    __syncthreads();  // drains vmcnt for global_load_lds

#pragma unroll
    for (int kk = 0; kk < 64; kk += 32) {
      const int qb = (kk >> 3) + quad;  // wanted global chunk
      short8 af[4], bf[4];
#pragma unroll
      for (int mi = 0; mi < 4; ++mi) {
        if (wm + (mi << 4) < rows) {    // frag-row live? (wave-uniform)
          const int r = wm + (mi << 4) + lr;
          af[mi] = *(const short8*)&As[r * 64 + ((qb ^ (r & 7)) << 3)];
        }
      }
#pragma unroll
      for (int ni = 0; ni < 4; ++ni) {
        const int r = wn + (ni << 4) + lr;
        bf[ni] = *(const short8*)&Bs[r * 64 + ((qb ^ (r & 7)) << 3)];
      }
#pragma unroll
      for (int mi = 0; mi < 4; ++mi) {
        if (wm + (mi << 4) < rows) {    // skip MFMAs of dead frag-rows
#pragma unroll
          for (int ni = 0; ni < 4; ++ni)
            acc[mi][ni] = __builtin_amdgcn_mfma_f32_16x16x32_bf16(af[mi], bf[ni], acc[mi][ni], 0, 0, 0);
        }
      }
    }
  }

  // Epilogue: relu -> bf16. C/D layout: col = lane&15, row = quad*4 + reg.
  const int pend = seg + cnt;
#pragma unroll
  for (int mi = 0; mi < 4; ++mi) {
    if (wm + (mi << 4) >= rows) continue;  // dead frag-row: nothing stored
#pragma unroll
    for (int ni = 0; ni < 4; ++ni) {
      const int col = n0 + wn + (ni << 4) + lr;
#pragma unroll
      for (int r4 = 0; r4 < 4; ++r4) {
        const int p = seg + m0 + wm + (mi << 4) + (quad << 2) + r4;
        if (p < pend) {
          float v = acc[mi][ni][r4];
          v = v > 0.f ? v : 0.f;
          O[(size_t)p * DIM + col] = f2bf(v);
        }
      }
    }
  }
}

// ---------------- combine: out[t] = w0*y[pos[2t]] + w1*y[pos[2t+1]] ----------
__global__ void combine_k(const u16* __restrict__ y, const int* __restrict__ pos,
                          const float* __restrict__ wts, float* __restrict__ out) {
  const int t    = blockIdx.x * 2 + (threadIdx.x >> 7);
  const int lane = threadIdx.x & 127;
  const int col  = lane * 8;
  const int p0 = pos[2 * t], p1 = pos[2 * t + 1];
  const float w0 = wts[2 * t], w1 = wts[2 * t + 1];
  const short8 a = *(const short8*)(y + (size_t)p0 * DIM + col);
  const short8 b = *(const short8*)(y + (size_t)p1 * DIM + col);
  f32x4 o0, o1;
#pragma unroll
  for (int j = 0; j < 8; ++j) {
    float v = w0 * bf2f((u16)a[j]) + w1 * bf2f((u16)b[j]);
    if (j < 4) o0[j] = v; else o1[j - 4] = v;
  }
  float* op = out + (size_t)t * DIM + col;
  *(f32x4*)op = o0;
  *(f32x4*)(op + 4) = o1;
}

extern "C" void kernel_launch(void* const* d_in, const int* in_sizes, int n_in,
                              void* d_out, int out_size, void* d_ws, size_t ws_size,
                              hipStream_t stream) {
  const float* x   = (const float*)d_in[0];
  const int*   idx = (const int*)d_in[1];
  const float* wts = (const float*)d_in[2];
  const float* W1  = (const float*)d_in[3];
  const float* W2  = (const float*)d_in[4];
  float* out = (float*)d_out;

  char* ws = (char*)d_ws;
  int* counts  = (int*)ws;                       // 8
  int* offsets = (int*)(ws + 32);                // 8
  int* ntiles  = (int*)(ws + 64);                // 1
  int* tlist   = (int*)(ws + 128);               // <=136
  int* bucket  = (int*)(ws + 1024);              // 16384
  int* pos     = (int*)(ws + 1024 + 4 * NPAIR);  // 16384
  const size_t base = 132096;                    // 16B-aligned
  const size_t MB16 = 16ull * 1024 * 1024;
  u16* xb  = (u16*)(ws + base);                  // 16 MB
  u16* w1b = (u16*)(ws + base + MB16);           // 16 MB
  u16* w2b = (u16*)(ws + base + 2 * MB16);       // 16 MB
  u16* h   = (u16*)(ws + base + 3 * MB16);       // 32 MB
  u16* yb  = xb;                                 // 32 MB, aliases xb+w1b (dead)

  // block 0 = sort (starts first, hides under the cast stream)
  prep_k<<<3 * 1024 + 1, 1024, 0, stream>>>(x, W1, W2, xb, w1b, w2b,
                                            idx, counts, offsets, bucket, pos,
                                            tlist, ntiles);

  // 1D grid: blocks 0..1023 = full tiles (slots 0..127), 1024..1087 = tail.
  moe_gemm_k<1><<<GEMM_BLKS, 256, 0, stream>>>(xb, w1b, h, counts, offsets, bucket, tlist, ntiles);
  moe_gemm_k<0><<<GEMM_BLKS, 256, 0, stream>>>(h, w2b, yb, counts, offsets, bucket, tlist, ntiles);

  combine_k<<<T_TOK / 2, 256, 0, stream>>>(yb, pos, wts, out);
}